// Round 1
// 150.445 us; speedup vs baseline: 1.0334x; 1.0334x over previous
//
#include <hip/hip_runtime.h>

#define LOG2E 1.4426950408889634f

typedef short bf16x8  __attribute__((ext_vector_type(8)));
typedef float f32x4   __attribute__((ext_vector_type(4)));
typedef float f32x16  __attribute__((ext_vector_type(16)));
typedef unsigned int u32x4 __attribute__((ext_vector_type(4)));

#if defined(__has_builtin)
#if __has_builtin(__builtin_amdgcn_exp2f)
#define EXP2F(v) __builtin_amdgcn_exp2f(v)
#else
#define EXP2F(v) exp2f(v)
#endif
#else
#define EXP2F(v) exp2f(v)
#endif

// fp32 -> bf16 round-to-nearest-even
__device__ __forceinline__ unsigned short f2bf(float f) {
  unsigned u = __float_as_uint(f);
  u += 0x7fffu + ((u >> 16) & 1u);
  return (unsigned short)(u >> 16);
}
// pack two fp32 -> bf16x2 (truncation; softmax weights only)
__device__ __forceinline__ unsigned pack2bf(float lo, float hi) {
  return (__float_as_uint(hi) & 0xffff0000u) | (__float_as_uint(lo) >> 16);
}
__device__ __forceinline__ f32x4 mfma16(bf16x8 a, bf16x8 b, f32x4 c) {
  return __builtin_amdgcn_mfma_f32_16x16x32_bf16(a, b, c, 0, 0, 0);
}
__device__ __forceinline__ f32x16 mfma32(bf16x8 a, bf16x8 b, f32x16 c) {
  return __builtin_amdgcn_mfma_f32_32x32x16_bf16(a, b, c, 0, 0, 0);
}
// global -> LDS direct DMA, 16 B per lane at ldsbase + lane*16
__device__ __forceinline__ void load_lds16(const unsigned short* g,
                                           unsigned short* l) {
  __builtin_amdgcn_global_load_lds(
      (const __attribute__((address_space(1))) unsigned int*)g,
      (__attribute__((address_space(3))) unsigned int*)l, 16, 0, 0);
}

// ---------------------------------------------------------------------------
// Projection R7: 64-px blocks, LDS-staged COALESCED stores.
// x[B,128,4096] fp32 -> qk[B][N][32] bf16 (0..15 = log2e*(Wq x + bq),
// 16..31 = Wk x + bk) and v[B][128][N] bf16 stored LINEARLY (the chunk
// swizzle moved into flash's DMA source addressing).
// Grid 512 = 8 b x 64 px-groups; block 256 = 4 waves; same wave->tile
// assignment as R5/R6, pixel-tile count doubled (rt 0..3).
// Store phase: qk = 16 B/lane fully contiguous (1 KB/instr); v = 8 rows x
// full 128 B line per instr. No partial-line scatter anywhere.
// ---------------------------------------------------------------------------
__global__ __launch_bounds__(256, 2) void proj_kernel(
    const float* __restrict__ x,
    const float* __restrict__ Wq, const float* __restrict__ bq,
    const float* __restrict__ Wk, const float* __restrict__ bk,
    const float* __restrict__ Wv, const float* __restrict__ bv,
    unsigned short* __restrict__ qk, unsigned short* __restrict__ vout)
{
  const int b  = blockIdx.x & 7;
  const int n0 = (blockIdx.x >> 3) << 6;      // 64 px per block
  const int tid  = threadIdx.x;
  const int wave = tid >> 6;
  const int lane = tid & 63;
  const int l15  = lane & 15;
  const int quad = lane >> 4;

  __shared__ unsigned short Xt[64][136];   // 17.4 KB  [px][ch], 16B-aligned rows
  __shared__ unsigned short Vst[128][72];  // 18.4 KB  [ch][px], 144 B rows
  __shared__ unsigned short Qst[64][40];   //  5.1 KB  [px][ch0..31], 80 B rows

  // ---- stage X^T: 256 B fully-coalesced global reads per instr ----
  {
    const int nn = tid & 63, cg = tid >> 6;   // cg 0..3
    const float* xr = x + (size_t)b * 128 * 4096 + n0 + nn;
    #pragma unroll
    for (int tb = 0; tb < 4; ++tb) {
      float xv[8];
      #pragma unroll
      for (int u = 0; u < 8; ++u)
        xv[u] = xr[(size_t)(cg + (((tb << 3) + u) << 2)) * 4096];
      #pragma unroll
      for (int u = 0; u < 8; ++u)
        Xt[nn][cg + (((tb << 3) + u) << 2)] = f2bf(xv[u]);
    }
  }
  __syncthreads();

  bf16x8 xa[4][4];
  #pragma unroll
  for (int rt = 0; rt < 4; ++rt)
    #pragma unroll
    for (int kt = 0; kt < 4; ++kt)
      xa[rt][kt] = *(const bf16x8*)&Xt[rt * 16 + l15][kt * 32 + quad * 8];

  const int nt0 = (wave < 2) ? wave * 3 : 6 + (wave - 2) * 2;
  const int ntc = (wave < 2) ? 3 : 2;

  f32x4 acc[4][3];
  #pragma unroll
  for (int rt = 0; rt < 4; ++rt)
    #pragma unroll
    for (int ni = 0; ni < 3; ++ni)
      acc[rt][ni] = (f32x4){0.f, 0.f, 0.f, 0.f};

  #pragma unroll
  for (int ni = 0; ni < 3; ++ni) {
    if (ni < ntc) {
      const int nt = nt0 + ni;
      const float* wrow;
      float sc = 1.f;
      if (nt == 0)      { wrow = Wq + l15 * 128; sc = LOG2E; }
      else if (nt == 1) { wrow = Wk + l15 * 128; }
      else              { wrow = Wv + (size_t)((nt - 2) * 16 + l15) * 128; }
      float4 wf[8];
      #pragma unroll
      for (int kt = 0; kt < 4; ++kt) {
        wf[2 * kt]     = *(const float4*)(wrow + kt * 32 + quad * 8);
        wf[2 * kt + 1] = *(const float4*)(wrow + kt * 32 + quad * 8 + 4);
      }
      #pragma unroll
      for (int kt = 0; kt < 4; ++kt) {
        const float4 f0 = wf[2 * kt], f1 = wf[2 * kt + 1];
        bf16x8 wb;
        wb[0] = (short)f2bf(sc * f0.x); wb[1] = (short)f2bf(sc * f0.y);
        wb[2] = (short)f2bf(sc * f0.z); wb[3] = (short)f2bf(sc * f0.w);
        wb[4] = (short)f2bf(sc * f1.x); wb[5] = (short)f2bf(sc * f1.y);
        wb[6] = (short)f2bf(sc * f1.z); wb[7] = (short)f2bf(sc * f1.w);
        #pragma unroll
        for (int rt = 0; rt < 4; ++rt)
          acc[rt][ni] = mfma16(xa[rt][kt], wb, acc[rt][ni]);
      }
    }
  }

  // ---- stage outputs into LDS ----
  #pragma unroll
  for (int ni = 0; ni < 3; ++ni) {
    if (ni < ntc) {
      const int nt = nt0 + ni;
      if (nt < 2) {
        const float bias = (nt == 0) ? LOG2E * bq[l15] : bk[l15];
        #pragma unroll
        for (int rt = 0; rt < 4; ++rt) {
          const int pb = rt * 16 + quad * 4;
          #pragma unroll
          for (int r = 0; r < 4; ++r)
            Qst[pb + r][nt * 16 + l15] = f2bf(acc[rt][ni][r] + bias);
        }
      } else {
        const int c = (nt - 2) * 16 + l15;
        const float bias = bv[c];
        #pragma unroll
        for (int rt = 0; rt < 4; ++rt) {
          ushort4 pk;
          pk.x = f2bf(acc[rt][ni][0] + bias);
          pk.y = f2bf(acc[rt][ni][1] + bias);
          pk.z = f2bf(acc[rt][ni][2] + bias);
          pk.w = f2bf(acc[rt][ni][3] + bias);
          *(ushort4*)&Vst[c][rt * 16 + quad * 4] = pk;
        }
      }
    }
  }
  __syncthreads();

  // ---- coalesced global stores ----
  {  // qk: 64 px x 32 ch = 4 KB contiguous; one 16 B granule per thread
    const int px = tid >> 2, ck = tid & 3;
    const uint4 val = *(const uint4*)&Qst[px][ck * 8];
    *(uint4*)&qk[((size_t)b * 4096 + n0 + px) * 32 + ck * 8] = val;
  }
  {  // v: 128 rows x 128 B (full lines per instr), linear layout
    const int cs = tid >> 3, s = tid & 7;
    #pragma unroll
    for (int r = 0; r < 4; ++r) {
      const int c = (r << 5) + cs;
      const uint4 val = *(const uint4*)&Vst[c][s * 8];
      *(uint4*)&vout[((size_t)b * 128 + c) * 4096 + n0 + s * 8] = val;
    }
  }
}

// ---------------------------------------------------------------------------
// Flash attention R7: identical core to R6 (32x32x16 MFMA, no-max softmax,
// LDS V via global_load_lds). Two changes:
//  (1) v is LINEAR in global; the 16B-chunk XOR swizzle is applied to the
//      per-lane DMA *source* address (LDS dest stays linear, rule-21
//      both-sides pattern) -> Vt layout and PV reads byte-identical to R6.
//  (2) Epilogue stages gamma*O/l through LDS (Vt dead after loop; aliased
//      as f32[64][132]) and stores out/x-add with 32 lanes covering a full
//      512 B row per instr -> kills the measured 4x write amplification.
// ---------------------------------------------------------------------------
__global__ __launch_bounds__(256, 3) void flash_kernel(
    const unsigned short* __restrict__ qk,
    const unsigned short* __restrict__ v,
    const float* __restrict__ x,
    const float* __restrict__ gamma,
    float* __restrict__ out)
{
  const int blk = blockIdx.x;
  const int b   = blk & 7;
  const int rg  = (blk >> 3) & 31;
  const int jh  = blk >> 8;            // 0..3
  const int tid  = threadIdx.x;
  const int w    = tid >> 6;
  const int lane = tid & 63;
  const int il   = lane & 31;
  const int h    = lane >> 5;

  // 33 KB: V tile (32 KB, [c][16B-chunk swizzled j]) / f32 out-stage [64][132]
  __shared__ float Obuf[64 * 132];
  unsigned short* const Vt = (unsigned short*)Obuf;

  const unsigned short* qkb = qk + (size_t)b * 4096 * 32;
  const unsigned short* vbB = v + (size_t)b * 128 * 4096;
  const int i0w = rg * 128 + w * 32;

  // Q B-frag: lane -> col i = il, k = h*8 + e (dense, all 64 lanes useful)
  const bf16x8 qa = *(const bf16x8*)(qkb + (size_t)(i0w + il) * 32 + h * 8);

  f32x16 o[4];
  #pragma unroll
  for (int ct = 0; ct < 4; ++ct)
    #pragma unroll
    for (int e = 0; e < 16; ++e) o[ct][e] = 0.f;
  float lsum = 0.f;

  const f32x16 z16 = o[0];
  const int sc_row = lane >> 4;            // staging: row within 4-row group
  const int sc16   = lane & 15;            // staging: dest chunk slot

  for (int t = 0; t < 8; ++t) {
    const int jbase = jh * 1024 + t * 128;

    // K A-frags: lane -> row j = jt*32+il, k = h*8+e. Global, pre-barrier.
    bf16x8 kf[4];
    #pragma unroll
    for (int jt = 0; jt < 4; ++jt)
      kf[jt] = *(const bf16x8*)(qkb + (size_t)(jbase + jt * 32 + il) * 32 +
                                16 + h * 8);

    __syncthreads();   // all waves done reading Vt(t-1)

    // V tile DMA: linear global rows, per-lane XOR-swizzled source chunk
    // -> Vt[c][s] = V[c][jbase/8 + (s ^ (c&7))], same layout as R6.
    #pragma unroll
    for (int k = 0; k < 8; ++k) {
      const int cbase = w * 32 + k * 4;
      const int crow  = cbase + sc_row;
      load_lds16(vbB + (size_t)crow * 4096 + jbase +
                     ((sc16 ^ (crow & 7)) << 3),
                 &Vt[cbase * 128]);
    }

    // S^T tiles + exp2 + in-register transpose to PV A-frags
    u32x4 A[8];
    #pragma unroll
    for (int jt = 0; jt < 4; ++jt) {
      f32x16 s = mfma32(kf[jt], qa, z16);
      float p[16];
      #pragma unroll
      for (int e = 0; e < 16; ++e) p[e] = EXP2F(s[e]);
      #pragma unroll
      for (int e = 0; e < 16; ++e) lsum += p[e];
      unsigned u[8], su[8];
      #pragma unroll
      for (int q = 0; q < 8; ++q) {
        u[q]  = pack2bf(p[2 * q], p[2 * q + 1]);
        su[q] = __shfl_xor(u[q], 32);
      }
      // A[jc] covers j = jt*32 + jc16*16 + h*8 + 0..7 for row i = il
      A[2 * jt]     = h ? (u32x4){su[2], su[3], u[2], u[3]}
                        : (u32x4){u[0], u[1], su[0], su[1]};
      A[2 * jt + 1] = h ? (u32x4){su[6], su[7], u[6], u[7]}
                        : (u32x4){u[4], u[5], su[4], su[5]};
    }

    __syncthreads();   // Vt(t) ready (drains DMA vmcnt)

    // PV: B-frag = V[c = ct*32+il][j chunk], swizzled LDS read
    #pragma unroll
    for (int jc = 0; jc < 8; ++jc) {
      const bf16x8 pa = __builtin_bit_cast(bf16x8, A[jc]);
      #pragma unroll
      for (int ct = 0; ct < 4; ++ct) {
        const bf16x8 vb = *(const bf16x8*)&Vt[(ct * 32 + il) * 128 +
                                              (((jc * 2 + h) ^ (il & 7)) << 3)];
        o[ct] = mfma32(pa, vb, o[ct]);
      }
    }
  }

  // ---- softmax denominator ----
  lsum += __shfl_xor(lsum, 32);            // lane il now holds l for row il
  float rl[16];
  #pragma unroll
  for (int e = 0; e < 16; ++e) {
    const int row = 4 * h + (e & 3) + 8 * (e >> 2);
    rl[e] = 1.f / __shfl(lsum, row);
  }

  // ---- epilogue: stage gamma*O/l in LDS, full-line coalesced out store ----
  const float g = gamma[0];
  #pragma unroll
  for (int half = 0; half < 2; ++half) {
    __syncthreads();   // half 0: PV reads of Vt done; half 1: prev reads done
    #pragma unroll
    for (int cc = 0; cc < 2; ++cc) {
      const int ct = half * 2 + cc;
      const int c_local = cc * 32 + il;    // 0..63
      #pragma unroll
      for (int e = 0; e < 16; ++e) {
        const int row = 4 * h + (e & 3) + 8 * (e >> 2);
        Obuf[c_local * 132 + w * 32 + row] = g * o[ct][e] * rl[e];
      }
    }
    __syncthreads();
    // 64 rows x 512 B; 32 lanes cover one full row per instr
    const int cr = tid >> 5;               // 0..7
    const int i4 = (tid & 31) * 4;
    #pragma unroll
    for (int rr = 0; rr < 8; ++rr) {
      const int c_local = rr * 8 + cr;
      const int c = half * 64 + c_local;
      const size_t idx = ((size_t)b * 128 + c) * 4096 + rg * 128 + i4;
      const float4 xv = *(const float4*)(x + idx);
      float4 ov = *(const float4*)&Obuf[c_local * 132 + i4];
      ov.x += xv.x; ov.y += xv.y; ov.z += xv.z; ov.w += xv.w;
      *(float4*)(out + idx) = ov;
    }
  }
}

extern "C" void kernel_launch(void* const* d_in, const int* in_sizes, int n_in,
                              void* d_out, int out_size, void* d_ws, size_t ws_size,
                              hipStream_t stream) {
  const float* x     = (const float*)d_in[0];
  const float* Wq    = (const float*)d_in[1];
  const float* bq    = (const float*)d_in[2];
  const float* Wk    = (const float*)d_in[3];
  const float* bk    = (const float*)d_in[4];
  const float* Wv    = (const float*)d_in[5];
  const float* bv    = (const float*)d_in[6];
  const float* gamma = (const float*)d_in[7];
  float* out = (float*)d_out;

  unsigned short* qkb = (unsigned short*)d_ws;         // 8*4096*32 bf16 = 2 MB
  unsigned short* vb  = qkb + (size_t)8 * 4096 * 32;   // 8*128*4096 bf16 = 8 MB

  proj_kernel<<<512, 256, 0, stream>>>(x, Wq, bq, Wk, bk, Wv, bv, qkb, vb);
  flash_kernel<<<1024, 256, 0, stream>>>(qkb, vb, x, gamma, out);
}